// Round 1
// baseline (37.532 us; speedup 1.0000x reference)
//
#include <hip/hip_runtime.h>

// out[b,t,n,:] = R(dof[b,t]) @ X[b,t,n,:] + T(dof[b,t])
// SE(3) exp: R = I + A K + B K^2,  V = I + B K + C K^2,  T = V v
// K = skew(w), K^2 = w w^T - |w|^2 I.

__global__ __launch_bounds__(256) void se3_apply_kernel(
    const float* __restrict__ X,
    const float* __restrict__ dof,
    float* __restrict__ out,
    int bps)              // blocks per (b,t) slice
{
    const int bt  = blockIdx.x / bps;
    const int sub = blockIdx.x % bps;

    // ---- per-transform math (redundant per thread; dof broadcast-cached) ----
    const float* d = dof + bt * 6;
    const float vx = d[0], vy = d[1], vz = d[2];
    const float wx = d[3], wy = d[4], wz = d[5];

    const float th2 = wx*wx + wy*wy + wz*wz;
    const float th  = sqrtf(th2);
    float A, Bc, C;
    if (th < 1e-4f) {
        A  = 1.0f - th2 * (1.0f/6.0f);
        Bc = 0.5f - th2 * (1.0f/24.0f);
        C  = (1.0f/6.0f) - th2 * (1.0f/120.0f);
    } else {
        const float s = sinf(th);
        const float c = cosf(th);
        A  = s / th;
        Bc = (1.0f - c) / th2;
        C  = (th - s) / (th2 * th);
    }

    // R = I + A*K + Bc*(w w^T - th2 I)
    const float r00 = 1.0f + Bc*(wx*wx - th2);
    const float r01 = Bc*wx*wy - A*wz;
    const float r02 = Bc*wx*wz + A*wy;
    const float r10 = Bc*wy*wx + A*wz;
    const float r11 = 1.0f + Bc*(wy*wy - th2);
    const float r12 = Bc*wy*wz - A*wx;
    const float r20 = Bc*wz*wx - A*wy;
    const float r21 = Bc*wz*wy + A*wx;
    const float r22 = 1.0f + Bc*(wz*wz - th2);

    // V = I + Bc*K + C*(w w^T - th2 I);  T = V v
    const float q00 = 1.0f + C*(wx*wx - th2);
    const float q01 = C*wx*wy - Bc*wz;
    const float q02 = C*wx*wz + Bc*wy;
    const float q10 = C*wy*wx + Bc*wz;
    const float q11 = 1.0f + C*(wy*wy - th2);
    const float q12 = C*wy*wz - Bc*wx;
    const float q20 = C*wz*wx - Bc*wy;
    const float q21 = C*wz*wy + Bc*wx;
    const float q22 = 1.0f + C*(wz*wz - th2);

    const float Tx = q00*vx + q01*vy + q02*vz;
    const float Ty = q10*vx + q11*vy + q12*vz;
    const float Tz = q20*vx + q21*vy + q22*vz;

    // ---- 4 points (12 floats = 3 float4) per thread, coalesced ----
    // slice has NP*3 floats; this block covers floats [sub*3072 .. sub*3072+3071]
    const int base = bt * (bps * 256 * 12) + sub * (256 * 12) + (int)threadIdx.x * 12;
    const float4* Xi = reinterpret_cast<const float4*>(X + base);
    float4*       Oi = reinterpret_cast<float4*>(out + base);

    const float4 a = Xi[0];
    const float4 b = Xi[1];
    const float4 c = Xi[2];

    // points: p0=(a.x,a.y,a.z) p1=(a.w,b.x,b.y) p2=(b.z,b.w,c.x) p3=(c.y,c.z,c.w)
    float o[12];
    {
        const float x = a.x, y = a.y, z = a.z;
        o[0] = fmaf(r00,x, fmaf(r01,y, fmaf(r02,z, Tx)));
        o[1] = fmaf(r10,x, fmaf(r11,y, fmaf(r12,z, Ty)));
        o[2] = fmaf(r20,x, fmaf(r21,y, fmaf(r22,z, Tz)));
    }
    {
        const float x = a.w, y = b.x, z = b.y;
        o[3] = fmaf(r00,x, fmaf(r01,y, fmaf(r02,z, Tx)));
        o[4] = fmaf(r10,x, fmaf(r11,y, fmaf(r12,z, Ty)));
        o[5] = fmaf(r20,x, fmaf(r21,y, fmaf(r22,z, Tz)));
    }
    {
        const float x = b.z, y = b.w, z = c.x;
        o[6] = fmaf(r00,x, fmaf(r01,y, fmaf(r02,z, Tx)));
        o[7] = fmaf(r10,x, fmaf(r11,y, fmaf(r12,z, Ty)));
        o[8] = fmaf(r20,x, fmaf(r21,y, fmaf(r22,z, Tz)));
    }
    {
        const float x = c.y, y = c.z, z = c.w;
        o[9]  = fmaf(r00,x, fmaf(r01,y, fmaf(r02,z, Tx)));
        o[10] = fmaf(r10,x, fmaf(r11,y, fmaf(r12,z, Ty)));
        o[11] = fmaf(r20,x, fmaf(r21,y, fmaf(r22,z, Tz)));
    }

    Oi[0] = make_float4(o[0], o[1], o[2],  o[3]);
    Oi[1] = make_float4(o[4], o[5], o[6],  o[7]);
    Oi[2] = make_float4(o[8], o[9], o[10], o[11]);
}

extern "C" void kernel_launch(void* const* d_in, const int* in_sizes, int n_in,
                              void* d_out, int out_size, void* d_ws, size_t ws_size,
                              hipStream_t stream) {
    const float* X   = (const float*)d_in[0];   // (B, NT, NP, 3) f32
    const float* dof = (const float*)d_in[1];   // (B, NT, 6) f32
    float* out = (float*)d_out;                 // (B, NT, NP, 3) f32

    const int BT = in_sizes[1] / 6;             // B*NT = 1024
    const int NP = in_sizes[0] / (BT * 3);      // 8192
    // each block covers 256 threads * 12 floats = 3072 floats = 1024 points
    const int bps = (NP * 3) / (256 * 12);      // 8 blocks per slice

    se3_apply_kernel<<<dim3(BT * bps), dim3(256), 0, stream>>>(X, dof, out, bps);
}

// Round 3
// 34.397 us; speedup vs baseline: 1.0911x; 1.0911x over previous
//
#include <hip/hip_runtime.h>

// out[b,t,n,:] = R(dof[b,t]) @ X[b,t,n,:] + T(dof[b,t])
// R = I + A K + B K^2, V = I + B K + C K^2, T = V v, K^2 = w w^T - |w|^2 I.
//
// All global traffic is dense unit-stride float4 via LDS staging.
// Stores are nontemporal so X (100.7 MB) stays resident in the 256 MB L3.

typedef float f4 __attribute__((ext_vector_type(4)));   // native vector: ok for nontemporal builtins

#define TPB 256
// tile = 1024 points = 3072 floats = 768 float4 = 12 KB LDS

__global__ __launch_bounds__(TPB) void se3_apply_kernel(
    const f4* __restrict__ X4,
    const float* __restrict__ dof,
    f4* __restrict__ O4,
    int bps)              // blocks per (b,t) slice
{
    __shared__ f4 lds4[768];
    __shared__ float rt[12];   // r00..r22, Tx,Ty,Tz

    const int bt  = blockIdx.x / bps;
    const int sub = blockIdx.x % bps;
    const int t   = (int)threadIdx.x;

    const int base4 = (bt * bps + sub) * 768;   // float4 index into X/out

    // ---- dense staging loads (issued before the uniform math) ----
    const f4 g0 = X4[base4 + t];
    const f4 g1 = X4[base4 + 256 + t];
    const f4 g2 = X4[base4 + 512 + t];

    // ---- thread 0 computes R,T once per block ----
    if (t == 0) {
        const float* d = dof + bt * 6;
        const float vx = d[0], vy = d[1], vz = d[2];
        const float wx = d[3], wy = d[4], wz = d[5];
        const float th2 = wx*wx + wy*wy + wz*wz;
        const float th  = sqrtf(th2);
        float A, Bc, C;
        if (th < 1e-4f) {
            A  = 1.0f - th2 * (1.0f/6.0f);
            Bc = 0.5f - th2 * (1.0f/24.0f);
            C  = (1.0f/6.0f) - th2 * (1.0f/120.0f);
        } else {
            const float s = sinf(th);
            const float c = cosf(th);
            A  = s / th;
            Bc = (1.0f - c) / th2;
            C  = (th - s) / (th2 * th);
        }
        rt[0] = 1.0f + Bc*(wx*wx - th2);
        rt[1] = Bc*wx*wy - A*wz;
        rt[2] = Bc*wx*wz + A*wy;
        rt[3] = Bc*wy*wx + A*wz;
        rt[4] = 1.0f + Bc*(wy*wy - th2);
        rt[5] = Bc*wy*wz - A*wx;
        rt[6] = Bc*wz*wx - A*wy;
        rt[7] = Bc*wz*wy + A*wx;
        rt[8] = 1.0f + Bc*(wz*wz - th2);
        const float q00 = 1.0f + C*(wx*wx - th2);
        const float q01 = C*wx*wy - Bc*wz;
        const float q02 = C*wx*wz + Bc*wy;
        const float q10 = C*wy*wx + Bc*wz;
        const float q11 = 1.0f + C*(wy*wy - th2);
        const float q12 = C*wy*wz - Bc*wx;
        const float q20 = C*wz*wx - Bc*wy;
        const float q21 = C*wz*wy + Bc*wx;
        const float q22 = 1.0f + C*(wz*wz - th2);
        rt[9]  = q00*vx + q01*vy + q02*vz;
        rt[10] = q10*vx + q11*vy + q12*vz;
        rt[11] = q20*vx + q21*vy + q22*vz;
    }

    lds4[t]       = g0;
    lds4[t + 256] = g1;
    lds4[t + 512] = g2;
    __syncthreads();

    const float r00 = rt[0], r01 = rt[1], r02 = rt[2];
    const float r10 = rt[3], r11 = rt[4], r12 = rt[5];
    const float r20 = rt[6], r21 = rt[7], r22 = rt[8];
    const float Tx  = rt[9], Ty = rt[10], Tz = rt[11];

    // ---- each thread transforms its 4 contiguous points in LDS ----
    const f4 a = lds4[3*t];
    const f4 b = lds4[3*t + 1];
    const f4 c = lds4[3*t + 2];

    f4 oa, ob, oc;
    {
        const float x = a.x, y = a.y, z = a.z;
        oa.x = fmaf(r00,x, fmaf(r01,y, fmaf(r02,z, Tx)));
        oa.y = fmaf(r10,x, fmaf(r11,y, fmaf(r12,z, Ty)));
        oa.z = fmaf(r20,x, fmaf(r21,y, fmaf(r22,z, Tz)));
    }
    {
        const float x = a.w, y = b.x, z = b.y;
        oa.w = fmaf(r00,x, fmaf(r01,y, fmaf(r02,z, Tx)));
        ob.x = fmaf(r10,x, fmaf(r11,y, fmaf(r12,z, Ty)));
        ob.y = fmaf(r20,x, fmaf(r21,y, fmaf(r22,z, Tz)));
    }
    {
        const float x = b.z, y = b.w, z = c.x;
        ob.z = fmaf(r00,x, fmaf(r01,y, fmaf(r02,z, Tx)));
        ob.w = fmaf(r10,x, fmaf(r11,y, fmaf(r12,z, Ty)));
        oc.x = fmaf(r20,x, fmaf(r21,y, fmaf(r22,z, Tz)));
    }
    {
        const float x = c.y, y = c.z, z = c.w;
        oc.y = fmaf(r00,x, fmaf(r01,y, fmaf(r02,z, Tx)));
        oc.z = fmaf(r10,x, fmaf(r11,y, fmaf(r12,z, Ty)));
        oc.w = fmaf(r20,x, fmaf(r21,y, fmaf(r22,z, Tz)));
    }

    lds4[3*t]     = oa;
    lds4[3*t + 1] = ob;
    lds4[3*t + 2] = oc;
    __syncthreads();

    // ---- dense nontemporal drain stores ----
    __builtin_nontemporal_store(lds4[t],       &O4[base4 + t]);
    __builtin_nontemporal_store(lds4[t + 256], &O4[base4 + 256 + t]);
    __builtin_nontemporal_store(lds4[t + 512], &O4[base4 + 512 + t]);
}

extern "C" void kernel_launch(void* const* d_in, const int* in_sizes, int n_in,
                              void* d_out, int out_size, void* d_ws, size_t ws_size,
                              hipStream_t stream) {
    const float* X   = (const float*)d_in[0];   // (B, NT, NP, 3) f32
    const float* dof = (const float*)d_in[1];   // (B, NT, 6) f32
    float* out = (float*)d_out;                 // (B, NT, NP, 3) f32

    const int BT = in_sizes[1] / 6;             // B*NT = 1024
    const int NP = in_sizes[0] / (BT * 3);      // 8192
    // each block covers 1024 points = 3072 floats = 768 float4
    const int bps = NP / 1024;                  // 8 blocks per slice

    se3_apply_kernel<<<dim3(BT * bps), dim3(TPB), 0, stream>>>(
        (const f4*)X, dof, (f4*)out, bps);
}